// Round 3
// baseline (848.723 us; speedup 1.0000x reference)
//
#include <hip/hip_runtime.h>
#include <stdint.h>

#define D_IN1 34   // msg MLP in: 12+12+8+1+1
#define H1    32
#define D_OUT1 24  // 8 (m_a) + 8 (m_b) + 8 (m_ab)
#define D_IN2 28   // upd MLP in: 8+8+12
#define H2    16
#define D_OUT2 8
#define CHN   12
#define CHE   8

__device__ __forceinline__ float clip100(float f) { return fminf(fmaxf(f, -100.f), 100.f); }

// ---- zero one contiguous region ----
__global__ void k_zero(int* __restrict__ p, int n_words) {
    int i = blockIdx.x * blockDim.x + threadIdx.x;
    if (i < n_words) p[i] = 0;
}

// ---- degrees via LDS histogram (wave-uniform fast path for sorted sources) ----
__global__ void k_degs(const int* __restrict__ src, const int* __restrict__ tgt,
                       int* __restrict__ outd, int* __restrict__ ind, int E, int N) {
    extern __shared__ int hist[];          // [2*N]
    int* ho = hist;
    int* hi = hist + N;
    for (int k = threadIdx.x; k < 2 * N; k += blockDim.x) hist[k] = 0;
    __syncthreads();
    for (int e = blockIdx.x * blockDim.x + threadIdx.x; e < E;
         e += gridDim.x * blockDim.x) {
        int s = src[e];
        int t = tgt[e];
        int s0 = __shfl(s, 0);
        unsigned long long act = __ballot(1);
        if (__all(s == s0)) {
            if ((threadIdx.x & 63) == 0) atomicAdd(&ho[s0], (int)__popcll(act));
        } else {
            atomicAdd(&ho[s], 1);
        }
        atomicAdd(&hi[t], 1);
    }
    __syncthreads();
    for (int k = threadIdx.x; k < N; k += blockDim.x) {
        int a = ho[k], b = hi[k];
        if (a) atomicAdd(&outd[k], a);
        if (b) atomicAdd(&ind[k], b);
    }
}

// ---- per-node layer-1 partials:
// SA[n][j] = sum_i W1[j][i]*node[i]        + W1[j][32]*outd[n]
// TB[n][j] = sum_i W1[j][12+i]*node[i]     + W1[j][33]*ind[n] + b1[j]
__launch_bounds__(256)
__global__ void k_pre(const float* __restrict__ nodes,
                      const int* __restrict__ outd, const int* __restrict__ ind,
                      const float* __restrict__ w1, const float* __restrict__ b1,
                      float* __restrict__ SA, float* __restrict__ TB,
                      int N, int total) {
    int i = blockIdx.x * blockDim.x + threadIdx.x;   // i = b*N + n
    if (i >= total) return;
    int n = i % N;

    float x[12];
    const float4* np = (const float4*)(nodes + (size_t)i * CHN);
    float4 n0 = np[0], n1 = np[1], n2 = np[2];
    x[0]=n0.x; x[1]=n0.y; x[2]=n0.z; x[3]=n0.w;
    x[4]=n1.x; x[5]=n1.y; x[6]=n1.z; x[7]=n1.w;
    x[8]=n2.x; x[9]=n2.y; x[10]=n2.z; x[11]=n2.w;
    float od  = (float)outd[n];
    float idg = (float)ind[n];

    float* sap = SA + (size_t)i * H1;
    float* tbp = TB + (size_t)i * H1;
#pragma unroll
    for (int h = 0; h < H1; ++h) {
        const float* wr = w1 + h * D_IN1;
        float a = wr[32] * od;
#pragma unroll
        for (int k = 0; k < 12; ++k) a = fmaf(wr[k], x[k], a);
        sap[h] = a;
        float c = fmaf(wr[33], idg, b1[h]);
#pragma unroll
        for (int k = 0; k < 12; ++k) c = fmaf(wr[12 + k], x[k], c);
        tbp[h] = c;
    }
}

// ---- per-edge MLP + edge update; agg_b into LDS [8][N] partial per block ----
// 512 threads, LDS 35.4KB -> 4 blocks/CU -> 32 waves/CU (100% cap); needs VGPR<=64.
__launch_bounds__(512, 8)
__global__ void k_edge(const float* __restrict__ edges,
                       const float* __restrict__ SA, const float* __restrict__ TB,
                       const float* __restrict__ w1, const float* __restrict__ w2,
                       const float* __restrict__ b2,
                       const int* __restrict__ src, const int* __restrict__ tgt,
                       float* __restrict__ agg_a, float* __restrict__ partials,
                       float* __restrict__ new_edges, int E, int N, int chunk, int nblk_alloc) {
    extern __shared__ float aggB[];        // [8][N], layout [c][t]
    int blk = blockIdx.x, b = blockIdx.y;
    int start = blk * chunk;
    if (start >= E) return;
    int end = min(E, start + chunk);

    for (int k = threadIdx.x; k < 8 * N; k += 512) aggB[k] = 0.f;
    __syncthreads();

    for (int base = start; base < end; base += 512) {
        int e = base + threadIdx.x;
        bool v = e < end;

        int s = -1, t = -1;
        float ma[8];
        float4 e0, e1;

        if (v) {
            s = src[e];
            t = tgt[e];

            const float4* ep = (const float4*)(edges + ((size_t)b * E + e) * CHE);
            e0 = ep[0]; e1 = ep[1];

            const float4* sap = (const float4*)(SA + ((size_t)b * N + s) * H1);
            const float4* tbp = (const float4*)(TB + ((size_t)b * N + t) * H1);

            // layer 1: h[j] = relu(SA[s][j] + TB[t][j] + W1e[j]·efeat)
            float h[H1];
#pragma unroll
            for (int q = 0; q < 8; ++q) {
                float4 a4 = sap[q];
                float4 c4 = tbp[q];
                float hv[4] = { a4.x + c4.x, a4.y + c4.y, a4.z + c4.z, a4.w + c4.w };
#pragma unroll
                for (int r = 0; r < 4; ++r) {
                    const float* wr = w1 + (4 * q + r) * D_IN1 + 24;
                    float a = hv[r];
                    a = fmaf(wr[0], e0.x, a); a = fmaf(wr[1], e0.y, a);
                    a = fmaf(wr[2], e0.z, a); a = fmaf(wr[3], e0.w, a);
                    a = fmaf(wr[4], e1.x, a); a = fmaf(wr[5], e1.y, a);
                    a = fmaf(wr[6], e1.z, a); a = fmaf(wr[7], e1.w, a);
                    h[4 * q + r] = fmaxf(a, 0.f);
                }
            }

            // layer 2, streamed to keep live ranges small:
            // m_a (o=0..7) kept for butterfly
#pragma unroll
            for (int o = 0; o < 8; ++o) {
                float a = b2[o];
#pragma unroll
                for (int j = 0; j < H1; ++j) a = fmaf(w2[o * H1 + j], h[j], a);
                ma[o] = a;
            }
            // m_b (o=8..15): consumed immediately by LDS atomic
#pragma unroll
            for (int o = 0; o < 8; ++o) {
                float a = b2[8 + o];
#pragma unroll
                for (int j = 0; j < H1; ++j) a = fmaf(w2[(8 + o) * H1 + j], h[j], a);
                atomicAdd(&aggB[o * N + t], a);
            }
            // m_ab (o=16..23): folded into edge output in place
            float mab[8];
#pragma unroll
            for (int o = 0; o < 8; ++o) {
                float a = b2[16 + o];
#pragma unroll
                for (int j = 0; j < H1; ++j) a = fmaf(w2[(16 + o) * H1 + j], h[j], a);
                mab[o] = a;
            }
            e0.x = clip100(e0.x + mab[0]); e0.y = clip100(e0.y + mab[1]);
            e0.z = clip100(e0.z + mab[2]); e0.w = clip100(e0.w + mab[3]);
            e1.x = clip100(e1.x + mab[4]); e1.y = clip100(e1.y + mab[5]);
            e1.z = clip100(e1.z + mab[6]); e1.w = clip100(e1.w + mab[7]);
            float4* ow = (float4*)(new_edges + ((size_t)b * E + e) * CHE);
            ow[0] = e0; ow[1] = e1;
        }

        // agg_a: sources in long runs -> usually wave-uniform; butterfly + 1 atomic/ch
        int s0 = __shfl(s, 0);
        bool fast = __all(v && s == s0);
        if (fast) {
            float* ga = agg_a + ((size_t)b * N + s0) * 8;
#pragma unroll
            for (int c = 0; c < 8; ++c) {
                float vv = ma[c];
#pragma unroll
                for (int off = 32; off; off >>= 1) vv += __shfl_xor(vv, off);
                if ((threadIdx.x & 63) == 0) atomicAdd(&ga[c], vv);
            }
        } else if (v) {
            float* ga = agg_a + ((size_t)b * N + s) * 8;
#pragma unroll
            for (int c = 0; c < 8; ++c) atomicAdd(&ga[c], ma[c]);
        }
    }

    __syncthreads();
    float* P = partials + ((size_t)b * nblk_alloc + blk) * 8 * N;
    for (int k = threadIdx.x; k < 8 * N; k += 512) P[k] = aggB[k];
}

// ---- sum per-block partials into agg_b [b][c][N]; p-dimension split P-way ----
__global__ void k_aggb(const float* __restrict__ partials, float* __restrict__ agg_b,
                       int nblk_used, int nblk_alloc, int span, int N, int totb) {
    int id = blockIdx.x * blockDim.x + threadIdx.x;
    if (id >= totb) return;
    int p0 = blockIdx.y * span;
    int p1 = min(nblk_used, p0 + span);
    if (p0 >= p1) return;
    int b = id / (8 * N);
    int r = id % (8 * N);
    float sum = 0.f;
    for (int p = p0; p < p1; ++p)
        sum += partials[((size_t)b * nblk_alloc + p) * 8 * N + r];
    atomicAdd(&agg_b[(size_t)b * 8 * N + r], sum);
}

// ---- per-node update MLP (agg_b layout [b][c][N]) ----
__launch_bounds__(256)
__global__ void k_upd(const float* __restrict__ nodes,
                      const float* __restrict__ agg_a, const float* __restrict__ agg_b,
                      const int* __restrict__ outd, const int* __restrict__ ind,
                      const float* __restrict__ u1, const float* __restrict__ ub1,
                      const float* __restrict__ u2, const float* __restrict__ ub2,
                      float* __restrict__ new_nodes, int N, int total) {
    int i = blockIdx.x * blockDim.x + threadIdx.x;
    if (i >= total) return;
    int b = i / N;
    int n = i % N;

    float rod = 1.f / fmaxf((float)outd[n], 1.f);
    float rdg = 1.f / fmaxf((float)ind[n], 1.f);

    float ux[D_IN2];
    const float4* ga = (const float4*)(agg_a + (size_t)i * 8);
    float4 a0 = ga[0], a1 = ga[1];
    ux[0] = a0.x * rod; ux[1] = a0.y * rod; ux[2] = a0.z * rod; ux[3] = a0.w * rod;
    ux[4] = a1.x * rod; ux[5] = a1.y * rod; ux[6] = a1.z * rod; ux[7] = a1.w * rod;
    const float* gb = agg_b + (size_t)b * 8 * N + n;
#pragma unroll
    for (int c = 0; c < 8; ++c) ux[8 + c] = gb[(size_t)c * N] * rdg;

    const float4* np4 = (const float4*)(nodes + (size_t)i * CHN);
    float4 n0 = np4[0], n1 = np4[1], n2 = np4[2];
    ux[16] = n0.x; ux[17] = n0.y; ux[18] = n0.z; ux[19] = n0.w;
    ux[20] = n1.x; ux[21] = n1.y; ux[22] = n1.z; ux[23] = n1.w;
    ux[24] = n2.x; ux[25] = n2.y; ux[26] = n2.z; ux[27] = n2.w;

    float hb[H2];
#pragma unroll
    for (int h = 0; h < H2; ++h) {
        float a = ub1[h];
#pragma unroll
        for (int k = 0; k < D_IN2; ++k) a = fmaf(u1[h * D_IN2 + k], ux[k], a);
        hb[h] = fmaxf(a, 0.f);
    }
    float up[D_OUT2];
#pragma unroll
    for (int o = 0; o < D_OUT2; ++o) {
        float a = ub2[o];
#pragma unroll
        for (int k = 0; k < H2; ++k) a = fmaf(u2[o * H2 + k], hb[k], a);
        up[o] = clip100(ux[16 + o] + a);
    }
    float4* onp = (float4*)(new_nodes + (size_t)i * CHN);
    onp[0] = make_float4(up[0], up[1], up[2], up[3]);
    onp[1] = make_float4(up[4], up[5], up[6], up[7]);
    onp[2] = n2;   // const channels 8..11 pass through
}

extern "C" void kernel_launch(void* const* d_in, const int* in_sizes, int n_in,
                              void* d_out, int out_size, void* d_ws, size_t ws_size,
                              hipStream_t stream) {
    const float* nodes = (const float*)d_in[0];
    const float* edges = (const float*)d_in[1];
    const float* mw1   = (const float*)d_in[2];
    const float* mb1   = (const float*)d_in[3];
    const float* mw2   = (const float*)d_in[4];
    const float* mb2   = (const float*)d_in[5];
    const float* uw1   = (const float*)d_in[6];
    const float* ubb1  = (const float*)d_in[7];
    const float* uw2   = (const float*)d_in[8];
    const float* ubb2  = (const float*)d_in[9];
    const int* src     = (const int*)d_in[10];
    const int* tgt     = (const int*)d_in[11];

    int E = in_sizes[10];
    int B = in_sizes[1] / (E * 8);
    int N = in_sizes[0] / (B * 12);

    // workspace: [outd | ind | pad | agg_a(B*8N) | agg_b(B*8N) | SA(B*N*32) | TB(B*N*32) | pad | partials]
    size_t off = 0;
    int* outd = (int*)((char*)d_ws + off);       off += (size_t)N * 4;
    int* ind  = (int*)((char*)d_ws + off);       off += (size_t)N * 4;
    off = (off + 63) & ~(size_t)63;
    float* agg_a = (float*)((char*)d_ws + off);  off += (size_t)B * N * 8 * 4;
    float* agg_b = (float*)((char*)d_ws + off);  off += (size_t)B * N * 8 * 4;
    size_t zbytes = off;                         // zero everything up to here
    float* SA = (float*)((char*)d_ws + off);     off += (size_t)B * N * H1 * 4;
    float* TB = (float*)((char*)d_ws + off);     off += (size_t)B * N * H1 * 4;
    off = (off + 63) & ~(size_t)63;
    float* partials = (float*)((char*)d_ws + off);

    // adaptive partial count: one [8][N] f32 slab per (batch, block)
    size_t per_blk = (size_t)B * 8 * N * sizeof(float);
    size_t avail = (ws_size > off) ? (ws_size - off) : 0;
    int nblk = (int)(avail / per_blk);
    if (nblk > 512) nblk = 512;     // grid 512*B = 1024 blocks = 4/CU (LDS-capped)
    if (nblk < 8)   nblk = 8;

    int zwords = (int)(zbytes / 4);
    k_zero<<<(zwords + 255) / 256, 256, 0, stream>>>((int*)d_ws, zwords);

    k_degs<<<256, 256, 2 * N * sizeof(int), stream>>>(src, tgt, outd, ind, E, N);

    int totn = B * N;
    k_pre<<<(totn + 255) / 256, 256, 0, stream>>>(nodes, outd, ind, mw1, mb1,
                                                  SA, TB, N, totn);

    float* out_nodes = (float*)d_out;
    float* out_edges = out_nodes + (size_t)B * N * 12;

    int chunk = (E + nblk - 1) / nblk;
    chunk = (chunk + 511) & ~511;               // dense 512-wide iterations
    int nblk_used = (E + chunk - 1) / chunk;

    dim3 ge(nblk_used, B);
    k_edge<<<ge, 512, 8 * N * sizeof(float), stream>>>(
        edges, SA, TB, mw1, mw2, mb2, src, tgt,
        agg_a, partials, out_edges, E, N, chunk, nblk);

    int totb = B * 8 * N;
    const int P = 16;
    int span = (nblk_used + P - 1) / P;
    dim3 ga((totb + 255) / 256, P);
    k_aggb<<<ga, 256, 0, stream>>>(partials, agg_b, nblk_used, nblk, span, N, totb);

    k_upd<<<(totn + 255) / 256, 256, 0, stream>>>(nodes, agg_a, agg_b, outd, ind,
                                                  uw1, ubb1, uw2, ubb2,
                                                  out_nodes, N, totn);
}

// Round 4
// 399.986 us; speedup vs baseline: 2.1219x; 2.1219x over previous
//
#include <hip/hip_runtime.h>
#include <stdint.h>

#define D_IN1 34   // msg MLP in: 12+12+8+1+1
#define H1    32
#define D_OUT1 24  // 8 (m_a) + 8 (m_b) + 8 (m_ab)
#define D_IN2 28   // upd MLP in: 8+8+12
#define H2    16
#define D_OUT2 8
#define CHN   12
#define CHE   8

__device__ __forceinline__ float clip100(float f) { return fminf(fmaxf(f, -100.f), 100.f); }

// ---- zero one contiguous region ----
__global__ void k_zero(int* __restrict__ p, int n_words) {
    int i = blockIdx.x * blockDim.x + threadIdx.x;
    if (i < n_words) p[i] = 0;
}

// ---- degrees via LDS histogram (wave-uniform fast path for sorted sources) ----
__global__ void k_degs(const int* __restrict__ src, const int* __restrict__ tgt,
                       int* __restrict__ outd, int* __restrict__ ind, int E, int N) {
    extern __shared__ int hist[];          // [2*N]
    int* ho = hist;
    int* hi = hist + N;
    for (int k = threadIdx.x; k < 2 * N; k += blockDim.x) hist[k] = 0;
    __syncthreads();
    for (int e = blockIdx.x * blockDim.x + threadIdx.x; e < E;
         e += gridDim.x * blockDim.x) {
        int s = src[e];
        int t = tgt[e];
        int s0 = __shfl(s, 0);
        unsigned long long act = __ballot(1);
        if (__all(s == s0)) {
            if ((threadIdx.x & 63) == 0) atomicAdd(&ho[s0], (int)__popcll(act));
        } else {
            atomicAdd(&ho[s], 1);
        }
        atomicAdd(&hi[t], 1);
    }
    __syncthreads();
    for (int k = threadIdx.x; k < N; k += blockDim.x) {
        int a = ho[k], b = hi[k];
        if (a) atomicAdd(&outd[k], a);
        if (b) atomicAdd(&ind[k], b);
    }
}

// ---- per-node layer-1 partials:
// SA[n][j] = sum_i W1[j][i]*node[i]        + W1[j][32]*outd[n]
// TB[n][j] = sum_i W1[j][12+i]*node[i]     + W1[j][33]*ind[n] + b1[j]
__launch_bounds__(256)
__global__ void k_pre(const float* __restrict__ nodes,
                      const int* __restrict__ outd, const int* __restrict__ ind,
                      const float* __restrict__ w1, const float* __restrict__ b1,
                      float* __restrict__ SA, float* __restrict__ TB,
                      int N, int total) {
    int i = blockIdx.x * blockDim.x + threadIdx.x;   // i = b*N + n
    if (i >= total) return;
    int n = i % N;

    float x[12];
    const float4* np = (const float4*)(nodes + (size_t)i * CHN);
    float4 n0 = np[0], n1 = np[1], n2 = np[2];
    x[0]=n0.x; x[1]=n0.y; x[2]=n0.z; x[3]=n0.w;
    x[4]=n1.x; x[5]=n1.y; x[6]=n1.z; x[7]=n1.w;
    x[8]=n2.x; x[9]=n2.y; x[10]=n2.z; x[11]=n2.w;
    float od  = (float)outd[n];
    float idg = (float)ind[n];

    float* sap = SA + (size_t)i * H1;
    float* tbp = TB + (size_t)i * H1;
#pragma unroll
    for (int h = 0; h < H1; ++h) {
        const float* wr = w1 + h * D_IN1;
        float a = wr[32] * od;
#pragma unroll
        for (int k = 0; k < 12; ++k) a = fmaf(wr[k], x[k], a);
        sap[h] = a;
        float c = fmaf(wr[33], idg, b1[h]);
#pragma unroll
        for (int k = 0; k < 12; ++k) c = fmaf(wr[12 + k], x[k], c);
        tbp[h] = c;
    }
}

// ---- per-edge MLP + edge update; agg_b into LDS [8][N] partial per block ----
// 512 threads, LDS 35.4KB -> 4 blocks/CU. NO min-waves hint: forcing 8 waves/EU
// made the allocator clamp to 32 VGPR -> catastrophic scratch spill (rounds 1,3:
// FETCH+WRITE 2.03GB, VALU 11-22%). Let the allocator float (~56-64 expected).
__launch_bounds__(512)
__global__ void k_edge(const float* __restrict__ edges,
                       const float* __restrict__ SA, const float* __restrict__ TB,
                       const float* __restrict__ w1, const float* __restrict__ w2,
                       const float* __restrict__ b2,
                       const int* __restrict__ src, const int* __restrict__ tgt,
                       float* __restrict__ agg_a, float* __restrict__ partials,
                       float* __restrict__ new_edges, int E, int N, int chunk, int nblk_alloc) {
    extern __shared__ float aggB[];        // [8][N], layout [c][t]
    int blk = blockIdx.x, b = blockIdx.y;
    int start = blk * chunk;
    if (start >= E) return;
    int end = min(E, start + chunk);

    for (int k = threadIdx.x; k < 8 * N; k += 512) aggB[k] = 0.f;
    __syncthreads();

    for (int base = start; base < end; base += 512) {
        int e = base + threadIdx.x;
        bool v = e < end;

        int s = -1, t = -1;
        float ma[8];
        float4 e0, e1;

        if (v) {
            s = src[e];
            t = tgt[e];

            const float4* ep = (const float4*)(edges + ((size_t)b * E + e) * CHE);
            e0 = ep[0]; e1 = ep[1];

            const float4* sap = (const float4*)(SA + ((size_t)b * N + s) * H1);
            const float4* tbp = (const float4*)(TB + ((size_t)b * N + t) * H1);

            // layer 1: h[j] = relu(SA[s][j] + TB[t][j] + W1e[j]·efeat)
            float h[H1];
#pragma unroll
            for (int q = 0; q < 8; ++q) {
                float4 a4 = sap[q];
                float4 c4 = tbp[q];
                float hv[4] = { a4.x + c4.x, a4.y + c4.y, a4.z + c4.z, a4.w + c4.w };
#pragma unroll
                for (int r = 0; r < 4; ++r) {
                    const float* wr = w1 + (4 * q + r) * D_IN1 + 24;
                    float a = hv[r];
                    a = fmaf(wr[0], e0.x, a); a = fmaf(wr[1], e0.y, a);
                    a = fmaf(wr[2], e0.z, a); a = fmaf(wr[3], e0.w, a);
                    a = fmaf(wr[4], e1.x, a); a = fmaf(wr[5], e1.y, a);
                    a = fmaf(wr[6], e1.z, a); a = fmaf(wr[7], e1.w, a);
                    h[4 * q + r] = fmaxf(a, 0.f);
                }
            }

            // layer 2, streamed to keep live ranges small:
            // m_a (o=0..7) kept for butterfly
#pragma unroll
            for (int o = 0; o < 8; ++o) {
                float a = b2[o];
#pragma unroll
                for (int j = 0; j < H1; ++j) a = fmaf(w2[o * H1 + j], h[j], a);
                ma[o] = a;
            }
            // m_b (o=8..15): consumed immediately by LDS atomic
#pragma unroll
            for (int o = 0; o < 8; ++o) {
                float a = b2[8 + o];
#pragma unroll
                for (int j = 0; j < H1; ++j) a = fmaf(w2[(8 + o) * H1 + j], h[j], a);
                atomicAdd(&aggB[o * N + t], a);
            }
            // m_ab (o=16..23): folded into edge output in place
            float mab[8];
#pragma unroll
            for (int o = 0; o < 8; ++o) {
                float a = b2[16 + o];
#pragma unroll
                for (int j = 0; j < H1; ++j) a = fmaf(w2[(16 + o) * H1 + j], h[j], a);
                mab[o] = a;
            }
            e0.x = clip100(e0.x + mab[0]); e0.y = clip100(e0.y + mab[1]);
            e0.z = clip100(e0.z + mab[2]); e0.w = clip100(e0.w + mab[3]);
            e1.x = clip100(e1.x + mab[4]); e1.y = clip100(e1.y + mab[5]);
            e1.z = clip100(e1.z + mab[6]); e1.w = clip100(e1.w + mab[7]);
            float4* ow = (float4*)(new_edges + ((size_t)b * E + e) * CHE);
            ow[0] = e0; ow[1] = e1;
        }

        // agg_a: sources in long runs -> usually wave-uniform; butterfly + 1 atomic/ch
        int s0 = __shfl(s, 0);
        bool fast = __all(v && s == s0);
        if (fast) {
            float* ga = agg_a + ((size_t)b * N + s0) * 8;
#pragma unroll
            for (int c = 0; c < 8; ++c) {
                float vv = ma[c];
#pragma unroll
                for (int off = 32; off; off >>= 1) vv += __shfl_xor(vv, off);
                if ((threadIdx.x & 63) == 0) atomicAdd(&ga[c], vv);
            }
        } else if (v) {
            float* ga = agg_a + ((size_t)b * N + s) * 8;
#pragma unroll
            for (int c = 0; c < 8; ++c) atomicAdd(&ga[c], ma[c]);
        }
    }

    __syncthreads();
    float* P = partials + ((size_t)b * nblk_alloc + blk) * 8 * N;
    for (int k = threadIdx.x; k < 8 * N; k += 512) P[k] = aggB[k];
}

// ---- sum per-block partials into agg_b [b][c][N]; p-dimension split P-way ----
__global__ void k_aggb(const float* __restrict__ partials, float* __restrict__ agg_b,
                       int nblk_used, int nblk_alloc, int span, int N, int totb) {
    int id = blockIdx.x * blockDim.x + threadIdx.x;
    if (id >= totb) return;
    int p0 = blockIdx.y * span;
    int p1 = min(nblk_used, p0 + span);
    if (p0 >= p1) return;
    int b = id / (8 * N);
    int r = id % (8 * N);
    float sum = 0.f;
    for (int p = p0; p < p1; ++p)
        sum += partials[((size_t)b * nblk_alloc + p) * 8 * N + r];
    atomicAdd(&agg_b[(size_t)b * 8 * N + r], sum);
}

// ---- per-node update MLP (agg_b layout [b][c][N]) ----
__launch_bounds__(256)
__global__ void k_upd(const float* __restrict__ nodes,
                      const float* __restrict__ agg_a, const float* __restrict__ agg_b,
                      const int* __restrict__ outd, const int* __restrict__ ind,
                      const float* __restrict__ u1, const float* __restrict__ ub1,
                      const float* __restrict__ u2, const float* __restrict__ ub2,
                      float* __restrict__ new_nodes, int N, int total) {
    int i = blockIdx.x * blockDim.x + threadIdx.x;
    if (i >= total) return;
    int b = i / N;
    int n = i % N;

    float rod = 1.f / fmaxf((float)outd[n], 1.f);
    float rdg = 1.f / fmaxf((float)ind[n], 1.f);

    float ux[D_IN2];
    const float4* ga = (const float4*)(agg_a + (size_t)i * 8);
    float4 a0 = ga[0], a1 = ga[1];
    ux[0] = a0.x * rod; ux[1] = a0.y * rod; ux[2] = a0.z * rod; ux[3] = a0.w * rod;
    ux[4] = a1.x * rod; ux[5] = a1.y * rod; ux[6] = a1.z * rod; ux[7] = a1.w * rod;
    const float* gb = agg_b + (size_t)b * 8 * N + n;
#pragma unroll
    for (int c = 0; c < 8; ++c) ux[8 + c] = gb[(size_t)c * N] * rdg;

    const float4* np4 = (const float4*)(nodes + (size_t)i * CHN);
    float4 n0 = np4[0], n1 = np4[1], n2 = np4[2];
    ux[16] = n0.x; ux[17] = n0.y; ux[18] = n0.z; ux[19] = n0.w;
    ux[20] = n1.x; ux[21] = n1.y; ux[22] = n1.z; ux[23] = n1.w;
    ux[24] = n2.x; ux[25] = n2.y; ux[26] = n2.z; ux[27] = n2.w;

    float hb[H2];
#pragma unroll
    for (int h = 0; h < H2; ++h) {
        float a = ub1[h];
#pragma unroll
        for (int k = 0; k < D_IN2; ++k) a = fmaf(u1[h * D_IN2 + k], ux[k], a);
        hb[h] = fmaxf(a, 0.f);
    }
    float up[D_OUT2];
#pragma unroll
    for (int o = 0; o < D_OUT2; ++o) {
        float a = ub2[o];
#pragma unroll
        for (int k = 0; k < H2; ++k) a = fmaf(u2[o * H2 + k], hb[k], a);
        up[o] = clip100(ux[16 + o] + a);
    }
    float4* onp = (float4*)(new_nodes + (size_t)i * CHN);
    onp[0] = make_float4(up[0], up[1], up[2], up[3]);
    onp[1] = make_float4(up[4], up[5], up[6], up[7]);
    onp[2] = n2;   // const channels 8..11 pass through
}

extern "C" void kernel_launch(void* const* d_in, const int* in_sizes, int n_in,
                              void* d_out, int out_size, void* d_ws, size_t ws_size,
                              hipStream_t stream) {
    const float* nodes = (const float*)d_in[0];
    const float* edges = (const float*)d_in[1];
    const float* mw1   = (const float*)d_in[2];
    const float* mb1   = (const float*)d_in[3];
    const float* mw2   = (const float*)d_in[4];
    const float* mb2   = (const float*)d_in[5];
    const float* uw1   = (const float*)d_in[6];
    const float* ubb1  = (const float*)d_in[7];
    const float* uw2   = (const float*)d_in[8];
    const float* ubb2  = (const float*)d_in[9];
    const int* src     = (const int*)d_in[10];
    const int* tgt     = (const int*)d_in[11];

    int E = in_sizes[10];
    int B = in_sizes[1] / (E * 8);
    int N = in_sizes[0] / (B * 12);

    // workspace: [outd | ind | pad | agg_a(B*8N) | agg_b(B*8N) | SA(B*N*32) | TB(B*N*32) | pad | partials]
    size_t off = 0;
    int* outd = (int*)((char*)d_ws + off);       off += (size_t)N * 4;
    int* ind  = (int*)((char*)d_ws + off);       off += (size_t)N * 4;
    off = (off + 63) & ~(size_t)63;
    float* agg_a = (float*)((char*)d_ws + off);  off += (size_t)B * N * 8 * 4;
    float* agg_b = (float*)((char*)d_ws + off);  off += (size_t)B * N * 8 * 4;
    size_t zbytes = off;                         // zero everything up to here
    float* SA = (float*)((char*)d_ws + off);     off += (size_t)B * N * H1 * 4;
    float* TB = (float*)((char*)d_ws + off);     off += (size_t)B * N * H1 * 4;
    off = (off + 63) & ~(size_t)63;
    float* partials = (float*)((char*)d_ws + off);

    // adaptive partial count: one [8][N] f32 slab per (batch, block)
    size_t per_blk = (size_t)B * 8 * N * sizeof(float);
    size_t avail = (ws_size > off) ? (ws_size - off) : 0;
    int nblk = (int)(avail / per_blk);
    if (nblk > 512) nblk = 512;     // grid 512*B = 1024 blocks = 4/CU (LDS-capped)
    if (nblk < 8)   nblk = 8;

    int zwords = (int)(zbytes / 4);
    k_zero<<<(zwords + 255) / 256, 256, 0, stream>>>((int*)d_ws, zwords);

    k_degs<<<256, 256, 2 * N * sizeof(int), stream>>>(src, tgt, outd, ind, E, N);

    int totn = B * N;
    k_pre<<<(totn + 255) / 256, 256, 0, stream>>>(nodes, outd, ind, mw1, mb1,
                                                  SA, TB, N, totn);

    float* out_nodes = (float*)d_out;
    float* out_edges = out_nodes + (size_t)B * N * 12;

    int chunk = (E + nblk - 1) / nblk;
    chunk = (chunk + 511) & ~511;               // dense 512-wide iterations
    int nblk_used = (E + chunk - 1) / chunk;

    dim3 ge(nblk_used, B);
    k_edge<<<ge, 512, 8 * N * sizeof(float), stream>>>(
        edges, SA, TB, mw1, mw2, mb2, src, tgt,
        agg_a, partials, out_edges, E, N, chunk, nblk);

    int totb = B * 8 * N;
    const int P = 16;
    int span = (nblk_used + P - 1) / P;
    dim3 ga((totb + 255) / 256, P);
    k_aggb<<<ga, 256, 0, stream>>>(partials, agg_b, nblk_used, nblk, span, N, totb);

    k_upd<<<(totn + 255) / 256, 256, 0, stream>>>(nodes, agg_a, agg_b, outd, ind,
                                                  uw1, ubb1, uw2, ubb2,
                                                  out_nodes, N, totn);
}